// Round 1
// baseline (892.921 us; speedup 1.0000x reference)
//
#include <hip/hip_runtime.h>
#include <math.h>

#define BATCH 16
#define HR 512
#define LR 128
#define N_LR (BATCH*LR*LR)   // 262144
#define N_HR (BATCH*HR*HR)   // 4194304
#define NSH 13
#define NSHIFT 169
#define PATCH 21
#define PR 10

__device__ __forceinline__ int clampi(int v, int lo, int hi){ return v<lo?lo:(v>hi?hi:v); }

// 7-tap gaussian, sigma=1, normalized. Called with compile-time t under unroll -> folds.
__device__ __forceinline__ float gk(int t){
  const float e1 = 0.60653065971263342f;   // exp(-0.5)
  const float e2 = 0.13533528323661270f;   // exp(-2)
  const float e3 = 0.011108996538242306f;  // exp(-4.5)
  const float norm = 1.0f/(1.0f + 2.0f*(e1+e2+e3));
  int a = t < 0 ? -t : t;
  float v = (a==0) ? 1.0f : (a==1 ? e1 : (a==2 ? e2 : e3));
  return v*norm;
}

// log1p(max(.,0)) + exact 4:1 downsample (bilinear frac=0.5 -> avg of rows/cols 4k+1,4k+2)
__global__ void k_downsample(const float* __restrict__ ref, const float* __restrict__ tar,
                             float* __restrict__ wref, float* __restrict__ wtar,
                             float* __restrict__ rain){
  int i = blockIdx.x*blockDim.x + threadIdx.x;
  if (i >= N_LR) return;
  int x = i & (LR-1); int y = (i >> 7) & (LR-1); int b = i >> 14;
  int base = b*HR*HR + (4*y+1)*HR + (4*x+1);
  float r00=ref[base], r01=ref[base+1], r10=ref[base+HR], r11=ref[base+HR+1];
  float t00=tar[base], t01=tar[base+1], t10=tar[base+HR], t11=tar[base+HR+1];
  wref[i] = 0.25f*(log1pf(fmaxf(r00,0.f))+log1pf(fmaxf(r01,0.f))
                 +log1pf(fmaxf(r10,0.f))+log1pf(fmaxf(r11,0.f)));
  wtar[i] = 0.25f*(log1pf(fmaxf(t00,0.f))+log1pf(fmaxf(t01,0.f))
                 +log1pf(fmaxf(t10,0.f))+log1pf(fmaxf(t11,0.f)));
  rain[i] = (0.25f*(t00+t01+t10+t11) >= 0.1f) ? 1.0f : 0.0f;
}

__global__ void k_blur_h(const float* __restrict__ in, float* __restrict__ out){
  int i = blockIdx.x*blockDim.x + threadIdx.x;
  if (i >= N_LR) return;
  int x = i & (LR-1); int rowbase = i - x;
  float s = 0.f;
  #pragma unroll
  for (int t=-3;t<=3;++t) s += gk(t)*in[rowbase + clampi(x+t,0,LR-1)];
  out[i] = s;
}

// vertical blur; optional mask multiply (for fx/fy: blur(f)*rain)
__global__ void k_blur_v(const float* __restrict__ in, float* __restrict__ out,
                         const float* __restrict__ mask){
  int i = blockIdx.x*blockDim.x + threadIdx.x;
  if (i >= N_LR) return;
  int x = i & (LR-1); int y = (i>>7)&(LR-1); int b = i>>14;
  float s = 0.f;
  #pragma unroll
  for (int t=-3;t<=3;++t) s += gk(t)*in[(b<<14) + (clampi(y+t,0,LR-1)<<7) + x];
  if (mask) s *= mask[i];
  out[i] = s;
}

// One block per (shift, batch): sliding separable 21x21 zero-pad box filter of
// (prev - shifted curr)^2, merged argmin via u64 atomicMin of (cost_bits<<32|s).
__global__ void k_cost(const float* __restrict__ prev, const float* __restrict__ curr,
                       unsigned long long* __restrict__ best){
  const int s  = blockIdx.x;            // 0..168
  const int b  = blockIdx.y;            // 0..15
  const int dy = s / NSH - 6;
  const int dx = s % NSH - 6;
  const int j  = threadIdx.x;           // 0..127 (one column each)
  const float* P = prev + (b<<14);
  const float* C = curr + (b<<14);
  unsigned long long* Bst = best + (b<<14);
  __shared__ float diffrow[LR];
  __shared__ float ring[PATCH][LR];
  const int cj = clampi(j+dx, 0, LR-1);
  float V = 0.f;
  for (int r = 0; r < LR + PR; ++r){
    float hs = 0.f;
    if (r < LR){
      int cr = clampi(r+dy, 0, LR-1);
      float d = P[(r<<7)+j] - C[(cr<<7)+cj];
      diffrow[j] = d*d;
    }
    __syncthreads();
    if (r < LR){
      #pragma unroll
      for (int t=-PR;t<=PR;++t){
        int c = j+t;
        if (c >= 0 && c < LR) hs += diffrow[c];
      }
      V += hs;
    }
    int old = r - PATCH;
    if (old >= 0) V -= ring[old % PATCH][j];   // same slot as write below (thread-local)
    if (r < LR) ring[r % PATCH][j] = hs;
    int i = r - PR;
    if (i >= 0){
      float cost = V * (1.0f/441.0f);
      unsigned long long key = ((unsigned long long)__float_as_uint(cost) << 32)
                             | (unsigned long long)s;
      unsigned long long* p = &Bst[(i<<7)+j];
      if (key < *p) atomicMin(p, key);   // stale read only over-triggers, never wrong
    }
    __syncthreads();
  }
}

__global__ void k_flow(const unsigned long long* __restrict__ best,
                       const float* __restrict__ rain,
                       float* __restrict__ fx, float* __restrict__ fy){
  int i = blockIdx.x*blockDim.x + threadIdx.x;
  if (i >= N_LR) return;
  unsigned int s = (unsigned int)(best[i] & 0xFFFFFFFFULL);
  float r = rain[i];
  fx[i] = (float)((int)(s % NSH) - 6) * r;
  fy[i] = (float)((int)(s / NSH) - 6) * r;
}

// Fused: flow upsample (x4), warp of ref (border bilinear), Huber+mask, mean-reduce.
__global__ void k_loss(const float* __restrict__ pred, const float* __restrict__ tar,
                       const float* __restrict__ ref, const float* __restrict__ fxb,
                       const float* __restrict__ fyb, float* __restrict__ out){
  int gid = blockIdx.x*blockDim.x + threadIdx.x;
  float acc = 0.f;
  if (gid < N_HR){
    int x = gid & (HR-1); int y = (gid>>9)&(HR-1); int b = gid>>18;
    // bilinear upsample of low-res flow: s = 0.25*o - 0.375 (clamped at 0)
    float sy = fmaxf(0.25f*(float)y - 0.375f, 0.f);
    float sx = fmaxf(0.25f*(float)x - 0.375f, 0.f);
    int y0 = min((int)sy, LR-1); int y1 = min(y0+1, LR-1); float wy = sy - (float)y0;
    int x0 = min((int)sx, LR-1); int x1 = min(x0+1, LR-1); float wx = sx - (float)x0;
    int lb = b<<14;
    float w00=(1.f-wy)*(1.f-wx), w01=(1.f-wy)*wx, w10=wy*(1.f-wx), w11=wy*wx;
    int i00 = lb+(y0<<7)+x0, i01 = lb+(y0<<7)+x1, i10 = lb+(y1<<7)+x0, i11 = lb+(y1<<7)+x1;
    float fx = 4.f*(w00*fxb[i00] + w01*fxb[i01] + w10*fxb[i10] + w11*fxb[i11]);
    float fy = 4.f*(w00*fyb[i00] + w01*fyb[i01] + w10*fyb[i10] + w11*fyb[i11]);
    // grid-sample coords simplify exactly to clip(x - fx, 0, 511)
    float ix = fminf(fmaxf((float)x - fx, 0.f), (float)(HR-1));
    float iy = fminf(fmaxf((float)y - fy, 0.f), (float)(HR-1));
    int gx0 = (int)ix; int gx1 = min(gx0+1, HR-1); float gwx = ix - (float)gx0;
    int gy0 = (int)iy; int gy1 = min(gy0+1, HR-1); float gwy = iy - (float)gy0;
    const float* R = ref + (b<<18);
    float v00 = R[(gy0<<9)+gx0], v01 = R[(gy0<<9)+gx1];
    float v10 = R[(gy1<<9)+gx0], v11 = R[(gy1<<9)+gx1];
    float t = v00*(1.f-gwy)*(1.f-gwx) + v01*(1.f-gwy)*gwx
            + v10*gwy*(1.f-gwx)       + v11*gwy*gwx;
    float teacher = fmaxf(t, 0.f);
    float d  = pred[gid] - teacher;
    float ad = fabsf(d);
    float l  = ad < 0.2f ? 0.5f*d*d : 0.2f*(ad - 0.1f);
    float m  = (teacher > 0.05f || tar[gid] > 0.05f) ? 1.f : 0.f;
    acc = l*m*(1.0f/(float)N_HR);
  }
  #pragma unroll
  for (int o = 32; o > 0; o >>= 1) acc += __shfl_down(acc, o, 64);
  __shared__ float wsum[4];
  int lane = threadIdx.x & 63, wv = threadIdx.x >> 6;
  if (lane == 0) wsum[wv] = acc;
  __syncthreads();
  if (threadIdx.x == 0) atomicAdd(out, wsum[0]+wsum[1]+wsum[2]+wsum[3]);
}

extern "C" void kernel_launch(void* const* d_in, const int* in_sizes, int n_in,
                              void* d_out, int out_size, void* d_ws, size_t ws_size,
                              hipStream_t stream){
  const float* pred = (const float*)d_in[0];
  const float* tar  = (const float*)d_in[1];
  const float* ref  = (const float*)d_in[2];
  float* out = (float*)d_out;
  float* w = (float*)d_ws;
  float* prevW = w + 0*N_LR;
  float* currW = w + 1*N_LR;
  float* tmp   = w + 2*N_LR;
  float* rain  = w + 3*N_LR;
  float* fxb   = w + 4*N_LR;
  float* fyb   = w + 5*N_LR;
  float* dsA   = w + 6*N_LR;   // wref_ds, later reused as raw fx
  float* dsB   = w + 7*N_LR;   // wtar_ds, later reused as raw fy
  unsigned long long* best = (unsigned long long*)(w + 8*N_LR);  // 2 MB, 8B-aligned

  hipMemsetAsync(best, 0xFF, (size_t)N_LR*sizeof(unsigned long long), stream);
  hipMemsetAsync(d_out, 0, sizeof(float), stream);

  const int tb = 256, nb = (N_LR + tb - 1)/tb;
  k_downsample<<<nb, tb, 0, stream>>>(ref, tar, dsA, dsB, rain);
  k_blur_h<<<nb, tb, 0, stream>>>(dsA, tmp);
  k_blur_v<<<nb, tb, 0, stream>>>(tmp, prevW, nullptr);
  k_blur_h<<<nb, tb, 0, stream>>>(dsB, tmp);
  k_blur_v<<<nb, tb, 0, stream>>>(tmp, currW, nullptr);
  k_cost<<<dim3(NSHIFT, BATCH), LR, 0, stream>>>(prevW, currW, best);
  k_flow<<<nb, tb, 0, stream>>>(best, rain, dsA, dsB);
  k_blur_h<<<nb, tb, 0, stream>>>(dsA, tmp);
  k_blur_v<<<nb, tb, 0, stream>>>(tmp, fxb, rain);
  k_blur_h<<<nb, tb, 0, stream>>>(dsB, tmp);
  k_blur_v<<<nb, tb, 0, stream>>>(tmp, fyb, rain);
  k_loss<<<(N_HR + tb - 1)/tb, tb, 0, stream>>>(pred, tar, ref, fxb, fyb, out);
}

// Round 2
// 479.663 us; speedup vs baseline: 1.8616x; 1.8616x over previous
//
#include <hip/hip_runtime.h>
#include <math.h>

#define BATCH 16
#define HR 512
#define LR 128
#define N_LR (BATCH*LR*LR)   // 262144
#define N_HR (BATCH*HR*HR)   // 4194304
#define NSH 13
#define NSHIFT 169
#define TH 8                 // output rows per k_cost block

__device__ __forceinline__ int clampi(int v, int lo, int hi){ return v<lo?lo:(v>hi?hi:v); }

// 7-tap gaussian, sigma=1, normalized; t compile-time under unroll -> folds.
__device__ __forceinline__ float gk(int t){
  const float e1 = 0.60653065971263342f;
  const float e2 = 0.13533528323661270f;
  const float e3 = 0.011108996538242306f;
  const float norm = 1.0f/(1.0f + 2.0f*(e1+e2+e3));
  int a = t < 0 ? -t : t;
  float v = (a==0) ? 1.0f : (a==1 ? e1 : (a==2 ? e2 : e3));
  return v*norm;
}

// log1p(max(.,0)) + exact 4:1 downsample (bilinear frac=0.5 -> avg of rows/cols 4k+1,4k+2)
__global__ void k_downsample(const float* __restrict__ ref, const float* __restrict__ tar,
                             float* __restrict__ wref, float* __restrict__ wtar,
                             float* __restrict__ rain){
  int i = blockIdx.x*blockDim.x + threadIdx.x;
  if (i >= N_LR) return;
  int x = i & (LR-1); int y = (i >> 7) & (LR-1); int b = i >> 14;
  int base = b*HR*HR + (4*y+1)*HR + (4*x+1);
  float r00=ref[base], r01=ref[base+1], r10=ref[base+HR], r11=ref[base+HR+1];
  float t00=tar[base], t01=tar[base+1], t10=tar[base+HR], t11=tar[base+HR+1];
  wref[i] = 0.25f*(log1pf(fmaxf(r00,0.f))+log1pf(fmaxf(r01,0.f))
                 +log1pf(fmaxf(r10,0.f))+log1pf(fmaxf(r11,0.f)));
  wtar[i] = 0.25f*(log1pf(fmaxf(t00,0.f))+log1pf(fmaxf(t01,0.f))
                 +log1pf(fmaxf(t10,0.f))+log1pf(fmaxf(t11,0.f)));
  rain[i] = (0.25f*(t00+t01+t10+t11) >= 0.1f) ? 1.0f : 0.0f;
}

// Fused separable 7x7 edge-clamped gaussian; blockIdx.z selects field pair.
// 16 output rows per block; LDS raw tile (22 rows) -> hblur -> vblur.
__global__ void k_blur2(const float* __restrict__ in0, const float* __restrict__ in1,
                        float* __restrict__ out0, float* __restrict__ out1,
                        const float* __restrict__ m0, const float* __restrict__ m1){
  const int z = blockIdx.z;
  const float* in  = z ? in1 : in0;
  float* out       = z ? out1 : out0;
  const float* msk = z ? m1 : m0;
  const int r0 = blockIdx.x * 16;
  const int bb = blockIdx.y;
  const int tid = threadIdx.x;
  const float* I = in + (bb<<14);
  __shared__ float raw[22][LR];
  __shared__ float hb[22][LR];
  for (int idx = tid; idx < 22*LR; idx += 256){
    int lr = idx >> 7, c = idx & (LR-1);
    int gr = clampi(r0 - 3 + lr, 0, LR-1);
    raw[lr][c] = I[(gr<<7) + c];
  }
  __syncthreads();
  for (int idx = tid; idx < 22*LR; idx += 256){
    int lr = idx >> 7, c = idx & (LR-1);
    float s = 0.f;
    #pragma unroll
    for (int t=-3;t<=3;++t) s += gk(t)*raw[lr][clampi(c+t,0,LR-1)];
    hb[lr][c] = s;
  }
  __syncthreads();
  for (int idx = tid; idx < 16*LR; idx += 256){
    int lr = idx >> 7, c = idx & (LR-1);
    int i = r0 + lr;
    float s = 0.f;
    #pragma unroll
    for (int t=-3;t<=3;++t) s += gk(t)*hb[clampi(i+t,0,LR-1) - (r0-3)][c];
    int gi = (bb<<14) + (i<<7) + c;
    if (msk) s *= msk[gi];
    out[gi] = s;
  }
}

// Block = (row-tile of 8, batch). 4 waves; wave w handles shifts s==w (mod 4),
// all 8 rows x 128 cols (2 cols/lane). Vertical 21-window slid per row; horizontal
// 21-tap via in-wave shuffle prefix + 2-tap difference. Register argmin; LDS merge;
// writes flow*rain directly (k_flow fused).
__global__ void __launch_bounds__(256)
k_cost_flow(const float* __restrict__ prev, const float* __restrict__ curr,
            const float* __restrict__ rain,
            float* __restrict__ fx, float* __restrict__ fy){
  const int r0 = blockIdx.x * TH;
  const int bb = blockIdx.y;
  const int tid = threadIdx.x;
  const int w = tid >> 6, lane = tid & 63;
  const int j0 = 2*lane;
  const float* P = prev + (bb<<14);
  const float* C = curr + (bb<<14);

  __shared__ __align__(16) union {
    struct { float prevT[28][LR]; float currT[40][140]; } t;
    unsigned long long merge[4][TH*LR];
  } sh;
  __shared__ float pfx[4][LR];

  for (int idx = tid; idx < 28*LR; idx += 256){
    int lr = idx >> 7, c = idx & (LR-1);
    int gr = r0 - 10 + lr;
    if (gr >= 0 && gr < LR) sh.t.prevT[lr][c] = P[(gr<<7) + c];
  }
  for (int idx = tid; idx < 40*140; idx += 256){
    int lr = idx / 140, c = idx - lr*140;
    int gr = r0 - 16 + lr;
    if (gr >= 0 && gr < LR) sh.t.currT[lr][c] = C[(gr<<7) + clampi(c-6,0,LR-1)];
  }
  __syncthreads();

  unsigned long long bk0[TH], bk1[TH];
  #pragma unroll
  for (int io=0; io<TH; ++io){ bk0[io] = ~0ULL; bk1[io] = ~0ULL; }

  for (int s = w; s < NSHIFT; s += 4){
    const int dy = s/NSH - 6, dx = s%NSH - 6;
    const int cb = dx + 6;
    float V0[TH], V1[TH];
    float v0 = 0.f, v1 = 0.f;
    #pragma unroll
    for (int u = -10; u <= 10; ++u){
      int r = r0 + u;
      if (r < 0 || r >= LR) continue;          // wave-uniform
      int lr = u + 10;
      int cr = clampi(r + dy, 0, LR-1) - r0 + 16;
      float2 p = *(const float2*)&sh.t.prevT[lr][j0];
      float c0 = sh.t.currT[cr][j0 + cb];
      float c1 = sh.t.currT[cr][j0 + 1 + cb];
      float d0 = p.x - c0, d1 = p.y - c1;
      v0 = fmaf(d0,d0,v0); v1 = fmaf(d1,d1,v1);
    }
    V0[0] = v0; V1[0] = v1;
    #pragma unroll
    for (int io = 1; io < TH; ++io){
      int i = r0 + io;
      int ra = i + 10;
      if (ra < LR){                            // uniform
        int lr = ra - r0 + 10;
        int cr = clampi(ra + dy, 0, LR-1) - r0 + 16;
        float2 p = *(const float2*)&sh.t.prevT[lr][j0];
        float c0 = sh.t.currT[cr][j0 + cb];
        float c1 = sh.t.currT[cr][j0 + 1 + cb];
        float d0 = p.x - c0, d1 = p.y - c1;
        v0 = fmaf(d0,d0,v0); v1 = fmaf(d1,d1,v1);
      }
      int rs = i - 11;
      if (rs >= 0){                            // uniform
        int lr = rs - r0 + 10;
        int cr = clampi(rs + dy, 0, LR-1) - r0 + 16;
        float2 p = *(const float2*)&sh.t.prevT[lr][j0];
        float c0 = sh.t.currT[cr][j0 + cb];
        float c1 = sh.t.currT[cr][j0 + 1 + cb];
        float d0 = p.x - c0, d1 = p.y - c1;
        v0 -= d0*d0; v1 -= d1*d1;
      }
      V0[io] = v0; V1[io] = v1;
    }
    #pragma unroll
    for (int io = 0; io < TH; ++io){
      float t = V0[io] + V1[io];
      float x = t;
      #pragma unroll
      for (int d = 1; d < 64; d <<= 1){
        float y = __shfl_up(x, d, 64);
        if (lane >= d) x += y;
      }
      float excl = x - t;
      float p0 = excl + V0[io];
      float p1 = p0 + V1[io];
      *(float2*)&pfx[w][j0] = make_float2(p0, p1);
      float a0 = pfx[w][min(j0+10, LR-1)];
      float a1 = pfx[w][min(j0+11, LR-1)];
      float b0r = pfx[w][max(j0-11, 0)];
      float b1r = pfx[w][max(j0-10, 0)];
      float b0 = (j0 >= 11) ? b0r : 0.f;
      float b1 = (j0 >= 10) ? b1r : 0.f;
      float c0 = fmaxf((a0-b0)*(1.0f/441.0f), 0.f);
      float c1 = fmaxf((a1-b1)*(1.0f/441.0f), 0.f);
      unsigned long long k0 = ((unsigned long long)__float_as_uint(c0)<<32) | (unsigned)s;
      unsigned long long k1 = ((unsigned long long)__float_as_uint(c1)<<32) | (unsigned)s;
      if (k0 < bk0[io]) bk0[io] = k0;
      if (k1 < bk1[io]) bk1[io] = k1;
    }
  }

  __syncthreads();   // all waves done reading tiles before union reuse
  #pragma unroll
  for (int io = 0; io < TH; ++io){
    sh.merge[w][io*LR + j0]     = bk0[io];
    sh.merge[w][io*LR + j0 + 1] = bk1[io];
  }
  __syncthreads();
  for (int p = tid; p < TH*LR; p += 256){
    unsigned long long k = sh.merge[0][p];
    unsigned long long k1 = sh.merge[1][p]; if (k1 < k) k = k1;
    unsigned long long k2 = sh.merge[2][p]; if (k2 < k) k = k2;
    unsigned long long k3 = sh.merge[3][p]; if (k3 < k) k = k3;
    int s = (int)(k & 0xffffffffULL);
    int io = p >> 7, jj = p & (LR-1);
    int gi = (bb<<14) + ((r0+io)<<7) + jj;
    float r = rain[gi];
    fx[gi] = (float)(s % NSH - 6) * r;
    fy[gi] = (float)(s / NSH - 6) * r;
  }
}

// Fused: flow upsample (x4), warp of ref (border bilinear), Huber+mask, mean-reduce.
__global__ void k_loss(const float* __restrict__ pred, const float* __restrict__ tar,
                       const float* __restrict__ ref, const float* __restrict__ fxb,
                       const float* __restrict__ fyb, float* __restrict__ out){
  int gid = blockIdx.x*blockDim.x + threadIdx.x;
  float acc = 0.f;
  if (gid < N_HR){
    int x = gid & (HR-1); int y = (gid>>9)&(HR-1); int b = gid>>18;
    float sy = fmaxf(0.25f*(float)y - 0.375f, 0.f);
    float sx = fmaxf(0.25f*(float)x - 0.375f, 0.f);
    int y0 = min((int)sy, LR-1); int y1 = min(y0+1, LR-1); float wy = sy - (float)y0;
    int x0 = min((int)sx, LR-1); int x1 = min(x0+1, LR-1); float wx = sx - (float)x0;
    int lb = b<<14;
    float w00=(1.f-wy)*(1.f-wx), w01=(1.f-wy)*wx, w10=wy*(1.f-wx), w11=wy*wx;
    int i00 = lb+(y0<<7)+x0, i01 = lb+(y0<<7)+x1, i10 = lb+(y1<<7)+x0, i11 = lb+(y1<<7)+x1;
    float fx = 4.f*(w00*fxb[i00] + w01*fxb[i01] + w10*fxb[i10] + w11*fxb[i11]);
    float fy = 4.f*(w00*fyb[i00] + w01*fyb[i01] + w10*fyb[i10] + w11*fyb[i11]);
    float ix = fminf(fmaxf((float)x - fx, 0.f), (float)(HR-1));
    float iy = fminf(fmaxf((float)y - fy, 0.f), (float)(HR-1));
    int gx0 = (int)ix; int gx1 = min(gx0+1, HR-1); float gwx = ix - (float)gx0;
    int gy0 = (int)iy; int gy1 = min(gy0+1, HR-1); float gwy = iy - (float)gy0;
    const float* R = ref + (b<<18);
    float v00 = R[(gy0<<9)+gx0], v01 = R[(gy0<<9)+gx1];
    float v10 = R[(gy1<<9)+gx0], v11 = R[(gy1<<9)+gx1];
    float t = v00*(1.f-gwy)*(1.f-gwx) + v01*(1.f-gwy)*gwx
            + v10*gwy*(1.f-gwx)       + v11*gwy*gwx;
    float teacher = fmaxf(t, 0.f);
    float d  = pred[gid] - teacher;
    float ad = fabsf(d);
    float l  = ad < 0.2f ? 0.5f*d*d : 0.2f*(ad - 0.1f);
    float m  = (teacher > 0.05f || tar[gid] > 0.05f) ? 1.f : 0.f;
    acc = l*m*(1.0f/(float)N_HR);
  }
  #pragma unroll
  for (int o = 32; o > 0; o >>= 1) acc += __shfl_down(acc, o, 64);
  __shared__ float wsum[4];
  int lane = threadIdx.x & 63, wv = threadIdx.x >> 6;
  if (lane == 0) wsum[wv] = acc;
  __syncthreads();
  if (threadIdx.x == 0) atomicAdd(out, wsum[0]+wsum[1]+wsum[2]+wsum[3]);
}

extern "C" void kernel_launch(void* const* d_in, const int* in_sizes, int n_in,
                              void* d_out, int out_size, void* d_ws, size_t ws_size,
                              hipStream_t stream){
  const float* pred = (const float*)d_in[0];
  const float* tar  = (const float*)d_in[1];
  const float* ref  = (const float*)d_in[2];
  float* out = (float*)d_out;
  float* w = (float*)d_ws;
  float* prevW = w + 0*N_LR;
  float* currW = w + 1*N_LR;
  float* rain  = w + 2*N_LR;
  float* fxb   = w + 3*N_LR;
  float* fyb   = w + 4*N_LR;
  float* dsA   = w + 5*N_LR;   // wref_ds, later reused as raw fx
  float* dsB   = w + 6*N_LR;   // wtar_ds, later reused as raw fy

  hipMemsetAsync(d_out, 0, sizeof(float), stream);

  const int tb = 256, nb = (N_LR + tb - 1)/tb;
  k_downsample<<<nb, tb, 0, stream>>>(ref, tar, dsA, dsB, rain);
  k_blur2<<<dim3(8, BATCH, 2), tb, 0, stream>>>(dsA, dsB, prevW, currW, nullptr, nullptr);
  k_cost_flow<<<dim3(LR/TH, BATCH), tb, 0, stream>>>(prevW, currW, rain, dsA, dsB);
  k_blur2<<<dim3(8, BATCH, 2), tb, 0, stream>>>(dsA, dsB, fxb, fyb, rain, rain);
  k_loss<<<(N_HR + tb - 1)/tb, tb, 0, stream>>>(pred, tar, ref, fxb, fyb, out);
}

// Round 3
// 217.171 us; speedup vs baseline: 4.1116x; 2.2087x over previous
//
#include <hip/hip_runtime.h>
#include <math.h>

#define BATCH 16
#define HR 512
#define LR 128
#define N_LR (BATCH*LR*LR)   // 262144
#define N_HR (BATCH*HR*HR)   // 4194304
#define NSH 13
#define NSHIFT 169
#define TH 8                 // output rows per k_cost block
#define CW 16                // waves per k_cost block

__device__ __forceinline__ int clampi(int v, int lo, int hi){ return v<lo?lo:(v>hi?hi:v); }

// 7-tap gaussian, sigma=1, normalized; t compile-time under unroll -> folds.
__device__ __forceinline__ float gk(int t){
  const float e1 = 0.60653065971263342f;
  const float e2 = 0.13533528323661270f;
  const float e3 = 0.011108996538242306f;
  const float norm = 1.0f/(1.0f + 2.0f*(e1+e2+e3));
  int a = t < 0 ? -t : t;
  float v = (a==0) ? 1.0f : (a==1 ? e1 : (a==2 ? e2 : e3));
  return v*norm;
}

// log1p(max(.,0)) + exact 4:1 downsample; dense float4 row loads (use .y/.z).
__global__ void k_downsample(const float* __restrict__ ref, const float* __restrict__ tar,
                             float* __restrict__ wref, float* __restrict__ wtar,
                             float* __restrict__ rain){
  int i = blockIdx.x*blockDim.x + threadIdx.x;
  if (i >= N_LR) return;
  int x = i & (LR-1); int y = (i >> 7) & (LR-1); int b = i >> 14;
  int base = b*HR*HR + (4*y+1)*HR + 4*x;      // 16B aligned
  float4 r1 = *(const float4*)(ref + base);
  float4 r2 = *(const float4*)(ref + base + HR);
  float4 t1 = *(const float4*)(tar + base);
  float4 t2 = *(const float4*)(tar + base + HR);
  float r00=r1.y, r01=r1.z, r10=r2.y, r11=r2.z;
  float t00=t1.y, t01=t1.z, t10=t2.y, t11=t2.z;
  wref[i] = 0.25f*(log1pf(fmaxf(r00,0.f))+log1pf(fmaxf(r01,0.f))
                 +log1pf(fmaxf(r10,0.f))+log1pf(fmaxf(r11,0.f)));
  wtar[i] = 0.25f*(log1pf(fmaxf(t00,0.f))+log1pf(fmaxf(t01,0.f))
                 +log1pf(fmaxf(t10,0.f))+log1pf(fmaxf(t11,0.f)));
  rain[i] = (0.25f*(t00+t01+t10+t11) >= 0.1f) ? 1.0f : 0.0f;
}

// Fused separable 7x7 edge-clamped gaussian; blockIdx.z selects field pair.
__global__ void k_blur2(const float* __restrict__ in0, const float* __restrict__ in1,
                        float* __restrict__ out0, float* __restrict__ out1,
                        const float* __restrict__ m0, const float* __restrict__ m1){
  const int z = blockIdx.z;
  const float* in  = z ? in1 : in0;
  float* out       = z ? out1 : out0;
  const float* msk = z ? m1 : m0;
  const int r0 = blockIdx.x * 16;
  const int bb = blockIdx.y;
  const int tid = threadIdx.x;
  const float* I = in + (bb<<14);
  __shared__ float raw[22][LR];
  __shared__ float hb[22][LR];
  for (int idx = tid; idx < 22*LR; idx += 256){
    int lr = idx >> 7, c = idx & (LR-1);
    int gr = clampi(r0 - 3 + lr, 0, LR-1);
    raw[lr][c] = I[(gr<<7) + c];
  }
  __syncthreads();
  for (int idx = tid; idx < 22*LR; idx += 256){
    int lr = idx >> 7, c = idx & (LR-1);
    float s = 0.f;
    #pragma unroll
    for (int t=-3;t<=3;++t) s += gk(t)*raw[lr][clampi(c+t,0,LR-1)];
    hb[lr][c] = s;
  }
  __syncthreads();
  for (int idx = tid; idx < 16*LR; idx += 256){
    int lr = idx >> 7, c = idx & (LR-1);
    int i = r0 + lr;
    float s = 0.f;
    #pragma unroll
    for (int t=-3;t<=3;++t) s += gk(t)*hb[clampi(i+t,0,LR-1) - (r0-3)][c];
    int gi = (bb<<14) + (i<<7) + c;
    if (msk) s *= msk[gi];
    out[gi] = s;
  }
}

// Block = (row-tile of 8, batch), 1024 threads = 16 waves. Wave w handles shifts
// s==w (mod 16), all 8 rows x 128 cols (2 cols/lane). Vertical 21-window slid per
// row; horizontal via in-wave shuffle prefix + 2-tap difference. Register argmin;
// slotted LDS tree merge; writes flow*rain directly.
__global__ void __launch_bounds__(1024)
k_cost_flow(const float* __restrict__ prev, const float* __restrict__ curr,
            const float* __restrict__ rain,
            float* __restrict__ fx, float* __restrict__ fy){
  const int r0 = blockIdx.x * TH;
  const int bb = blockIdx.y;
  const int tid = threadIdx.x;
  const int w = tid >> 6, lane = tid & 63;
  const int j0 = 2*lane;
  const float* P = prev + (bb<<14);
  const float* C = curr + (bb<<14);

  __shared__ __align__(16) union {
    struct { float prevT[28][LR]; float currT[40][140]; } t;   // 36736 B
    unsigned long long merge[4][TH*LR];                        // 32768 B
  } sh;
  __shared__ float pfx[CW][LR];                                // 8192 B

  for (int idx = tid; idx < 28*LR; idx += 1024){
    int lr = idx >> 7, c = idx & (LR-1);
    int gr = r0 - 10 + lr;
    if (gr >= 0 && gr < LR) sh.t.prevT[lr][c] = P[(gr<<7) + c];
  }
  for (int idx = tid; idx < 40*140; idx += 1024){
    int lr = idx / 140, c = idx - lr*140;
    int gr = r0 - 16 + lr;
    if (gr >= 0 && gr < LR) sh.t.currT[lr][c] = C[(gr<<7) + clampi(c-6,0,LR-1)];
  }
  __syncthreads();

  unsigned long long bk0[TH], bk1[TH];
  #pragma unroll
  for (int io=0; io<TH; ++io){ bk0[io] = ~0ULL; bk1[io] = ~0ULL; }

  for (int s = w; s < NSHIFT; s += CW){
    const int dy = s/NSH - 6, dx = s%NSH - 6;
    const int cb = dx + 6;
    float V0[TH], V1[TH];
    float v0 = 0.f, v1 = 0.f;
    #pragma unroll
    for (int u = -10; u <= 10; ++u){
      int r = r0 + u;
      if (r < 0 || r >= LR) continue;          // wave-uniform
      int lr = u + 10;
      int cr = clampi(r + dy, 0, LR-1) - r0 + 16;
      float2 p = *(const float2*)&sh.t.prevT[lr][j0];
      float c0 = sh.t.currT[cr][j0 + cb];
      float c1 = sh.t.currT[cr][j0 + 1 + cb];
      float d0 = p.x - c0, d1 = p.y - c1;
      v0 = fmaf(d0,d0,v0); v1 = fmaf(d1,d1,v1);
    }
    V0[0] = v0; V1[0] = v1;
    #pragma unroll
    for (int io = 1; io < TH; ++io){
      int i = r0 + io;
      int ra = i + 10;
      if (ra < LR){                            // uniform
        int lr = ra - r0 + 10;
        int cr = clampi(ra + dy, 0, LR-1) - r0 + 16;
        float2 p = *(const float2*)&sh.t.prevT[lr][j0];
        float c0 = sh.t.currT[cr][j0 + cb];
        float c1 = sh.t.currT[cr][j0 + 1 + cb];
        float d0 = p.x - c0, d1 = p.y - c1;
        v0 = fmaf(d0,d0,v0); v1 = fmaf(d1,d1,v1);
      }
      int rs = i - 11;
      if (rs >= 0){                            // uniform
        int lr = rs - r0 + 10;
        int cr = clampi(rs + dy, 0, LR-1) - r0 + 16;
        float2 p = *(const float2*)&sh.t.prevT[lr][j0];
        float c0 = sh.t.currT[cr][j0 + cb];
        float c1 = sh.t.currT[cr][j0 + 1 + cb];
        float d0 = p.x - c0, d1 = p.y - c1;
        v0 -= d0*d0; v1 -= d1*d1;
      }
      V0[io] = v0; V1[io] = v1;
    }
    #pragma unroll
    for (int io = 0; io < TH; ++io){
      float t = V0[io] + V1[io];
      float x = t;
      #pragma unroll
      for (int d = 1; d < 64; d <<= 1){
        float y = __shfl_up(x, d, 64);
        if (lane >= d) x += y;
      }
      float excl = x - t;
      float p0 = excl + V0[io];
      float p1 = p0 + V1[io];
      *(float2*)&pfx[w][j0] = make_float2(p0, p1);
      float a0 = pfx[w][min(j0+10, LR-1)];
      float a1 = pfx[w][min(j0+11, LR-1)];
      float b0r = pfx[w][max(j0-11, 0)];
      float b1r = pfx[w][max(j0-10, 0)];
      float b0 = (j0 >= 11) ? b0r : 0.f;
      float b1 = (j0 >= 10) ? b1r : 0.f;
      float c0 = fmaxf((a0-b0)*(1.0f/441.0f), 0.f);
      float c1 = fmaxf((a1-b1)*(1.0f/441.0f), 0.f);
      unsigned long long k0 = ((unsigned long long)__float_as_uint(c0)<<32) | (unsigned)s;
      unsigned long long k1 = ((unsigned long long)__float_as_uint(c1)<<32) | (unsigned)s;
      if (k0 < bk0[io]) bk0[io] = k0;
      if (k1 < bk1[io]) bk1[io] = k1;
    }
  }

  __syncthreads();   // all waves done reading tiles before union reuse
  // Slotted tree merge: slot g = w&3; waves g, g+4, g+8, g+12 serialize into slot g.
  const int g = w & 3;
  #pragma unroll
  for (int round = 0; round < 4; ++round){
    if ((w >> 2) == round){
      if (round == 0){
        #pragma unroll
        for (int io = 0; io < TH; ++io){
          sh.merge[g][io*LR + j0]     = bk0[io];
          sh.merge[g][io*LR + j0 + 1] = bk1[io];
        }
      } else {
        #pragma unroll
        for (int io = 0; io < TH; ++io){
          unsigned long long m0 = sh.merge[g][io*LR + j0];
          unsigned long long m1 = sh.merge[g][io*LR + j0 + 1];
          sh.merge[g][io*LR + j0]     = (bk0[io] < m0) ? bk0[io] : m0;
          sh.merge[g][io*LR + j0 + 1] = (bk1[io] < m1) ? bk1[io] : m1;
        }
      }
    }
    __syncthreads();
  }
  {
    int p = tid;                       // 1024 threads, TH*LR = 1024 pixels
    unsigned long long k = sh.merge[0][p];
    unsigned long long k1 = sh.merge[1][p]; if (k1 < k) k = k1;
    unsigned long long k2 = sh.merge[2][p]; if (k2 < k) k = k2;
    unsigned long long k3 = sh.merge[3][p]; if (k3 < k) k = k3;
    int s = (int)(k & 0xffffffffULL);
    int io = p >> 7, jj = p & (LR-1);
    int gi = (bb<<14) + ((r0+io)<<7) + jj;
    float r = rain[gi];
    fx[gi] = (float)(s % NSH - 6) * r;
    fy[gi] = (float)(s / NSH - 6) * r;
  }
}

// Fused: flow upsample (x4), warp of ref (border bilinear), Huber+mask, mean-reduce.
// Grid-stride; each thread owns groups of 4 consecutive px (float4 pred/tar).
__global__ void __launch_bounds__(256)
k_loss(const float* __restrict__ pred, const float* __restrict__ tar,
       const float* __restrict__ ref, const float* __restrict__ fxb,
       const float* __restrict__ fyb, float* __restrict__ out){
  const int nthreads = gridDim.x * 256;
  float acc = 0.f;
  for (int gq = blockIdx.x*256 + threadIdx.x; gq < N_HR/4; gq += nthreads){
    int b   = gq >> 16;                 // 65536 groups per image
    int rem = gq & 65535;
    int y   = rem >> 7;
    int x4  = (rem & 127) << 2;
    float sy = fmaxf(0.25f*(float)y - 0.375f, 0.f);
    int y0 = min((int)sy, LR-1); int y1 = min(y0+1, LR-1); float wy = sy - (float)y0;
    int lb = b<<14;
    const float* Fx0 = fxb + lb + (y0<<7);
    const float* Fx1 = fxb + lb + (y1<<7);
    const float* Fy0 = fyb + lb + (y0<<7);
    const float* Fy1 = fyb + lb + (y1<<7);
    int hb = (b<<18) + (y<<9) + x4;
    float4 pd = *(const float4*)(pred + hb);
    float4 td = *(const float4*)(tar + hb);
    const float* R = ref + (b<<18);
    #pragma unroll
    for (int k = 0; k < 4; ++k){
      int x = x4 + k;
      float sx = fmaxf(0.25f*(float)x - 0.375f, 0.f);
      int x0 = min((int)sx, LR-1); int x1 = min(x0+1, LR-1); float wx = sx - (float)x0;
      float w00=(1.f-wy)*(1.f-wx), w01=(1.f-wy)*wx, w10=wy*(1.f-wx), w11=wy*wx;
      float fxv = 4.f*(w00*Fx0[x0] + w01*Fx0[x1] + w10*Fx1[x0] + w11*Fx1[x1]);
      float fyv = 4.f*(w00*Fy0[x0] + w01*Fy0[x1] + w10*Fy1[x0] + w11*Fy1[x1]);
      float ix = fminf(fmaxf((float)x - fxv, 0.f), (float)(HR-1));
      float iy = fminf(fmaxf((float)y - fyv, 0.f), (float)(HR-1));
      int gx0 = (int)ix; int gx1 = min(gx0+1, HR-1); float gwx = ix - (float)gx0;
      int gy0 = (int)iy; int gy1 = min(gy0+1, HR-1); float gwy = iy - (float)gy0;
      float v00 = R[(gy0<<9)+gx0], v01 = R[(gy0<<9)+gx1];
      float v10 = R[(gy1<<9)+gx0], v11 = R[(gy1<<9)+gx1];
      float t = v00*(1.f-gwy)*(1.f-gwx) + v01*(1.f-gwy)*gwx
              + v10*gwy*(1.f-gwx)       + v11*gwy*gwx;
      float teacher = fmaxf(t, 0.f);
      float pk = ((const float*)&pd)[k];
      float tk = ((const float*)&td)[k];
      float d  = pk - teacher;
      float ad = fabsf(d);
      float l  = ad < 0.2f ? 0.5f*d*d : 0.2f*(ad - 0.1f);
      float m  = (teacher > 0.05f || tk > 0.05f) ? 1.f : 0.f;
      acc += l*m;
    }
  }
  acc *= (1.0f/(float)N_HR);
  #pragma unroll
  for (int o = 32; o > 0; o >>= 1) acc += __shfl_down(acc, o, 64);
  __shared__ float wsum[4];
  int lane = threadIdx.x & 63, wv = threadIdx.x >> 6;
  if (lane == 0) wsum[wv] = acc;
  __syncthreads();
  if (threadIdx.x == 0) atomicAdd(out, wsum[0]+wsum[1]+wsum[2]+wsum[3]);
}

extern "C" void kernel_launch(void* const* d_in, const int* in_sizes, int n_in,
                              void* d_out, int out_size, void* d_ws, size_t ws_size,
                              hipStream_t stream){
  const float* pred = (const float*)d_in[0];
  const float* tar  = (const float*)d_in[1];
  const float* ref  = (const float*)d_in[2];
  float* out = (float*)d_out;
  float* w = (float*)d_ws;
  float* prevW = w + 0*N_LR;
  float* currW = w + 1*N_LR;
  float* rain  = w + 2*N_LR;
  float* fxb   = w + 3*N_LR;
  float* fyb   = w + 4*N_LR;
  float* dsA   = w + 5*N_LR;   // wref_ds, later reused as raw fx
  float* dsB   = w + 6*N_LR;   // wtar_ds, later reused as raw fy

  hipMemsetAsync(d_out, 0, sizeof(float), stream);

  const int tb = 256, nb = (N_LR + tb - 1)/tb;
  k_downsample<<<nb, tb, 0, stream>>>(ref, tar, dsA, dsB, rain);
  k_blur2<<<dim3(8, BATCH, 2), tb, 0, stream>>>(dsA, dsB, prevW, currW, nullptr, nullptr);
  k_cost_flow<<<dim3(LR/TH, BATCH), 1024, 0, stream>>>(prevW, currW, rain, dsA, dsB);
  k_blur2<<<dim3(8, BATCH, 2), tb, 0, stream>>>(dsA, dsB, fxb, fyb, rain, rain);
  k_loss<<<2048, tb, 0, stream>>>(pred, tar, ref, fxb, fyb, out);
}

// Round 4
// 191.229 us; speedup vs baseline: 4.6694x; 1.1357x over previous
//
#include <hip/hip_runtime.h>
#include <math.h>

#define BATCH 16
#define HR 512
#define LR 128
#define N_LR (BATCH*LR*LR)   // 262144
#define N_HR (BATCH*HR*HR)   // 4194304
#define NSH 13
#define NSHIFT 169
#define TH 8                 // output rows per k_cost block
#define NW 8                 // waves per k_cost block

__device__ __forceinline__ int clampi(int v, int lo, int hi){ return v<lo?lo:(v>hi?hi:v); }

// 7-tap gaussian, sigma=1, normalized; t compile-time under unroll -> folds.
__device__ __forceinline__ float gk(int t){
  const float e1 = 0.60653065971263342f;
  const float e2 = 0.13533528323661270f;
  const float e3 = 0.011108996538242306f;
  const float norm = 1.0f/(1.0f + 2.0f*(e1+e2+e3));
  int a = t < 0 ? -t : t;
  float v = (a==0) ? 1.0f : (a==1 ? e1 : (a==2 ? e2 : e3));
  return v*norm;
}

// log1p(max(.,0)) + exact 4:1 downsample; dense float4 row loads (use .y/.z).
__global__ void k_downsample(const float* __restrict__ ref, const float* __restrict__ tar,
                             float* __restrict__ wref, float* __restrict__ wtar,
                             float* __restrict__ rain){
  int i = blockIdx.x*blockDim.x + threadIdx.x;
  if (i >= N_LR) return;
  int x = i & (LR-1); int y = (i >> 7) & (LR-1); int b = i >> 14;
  int base = b*HR*HR + (4*y+1)*HR + 4*x;      // 16B aligned
  float4 r1 = *(const float4*)(ref + base);
  float4 r2 = *(const float4*)(ref + base + HR);
  float4 t1 = *(const float4*)(tar + base);
  float4 t2 = *(const float4*)(tar + base + HR);
  float r00=r1.y, r01=r1.z, r10=r2.y, r11=r2.z;
  float t00=t1.y, t01=t1.z, t10=t2.y, t11=t2.z;
  wref[i] = 0.25f*(log1pf(fmaxf(r00,0.f))+log1pf(fmaxf(r01,0.f))
                 +log1pf(fmaxf(r10,0.f))+log1pf(fmaxf(r11,0.f)));
  wtar[i] = 0.25f*(log1pf(fmaxf(t00,0.f))+log1pf(fmaxf(t01,0.f))
                 +log1pf(fmaxf(t10,0.f))+log1pf(fmaxf(t11,0.f)));
  rain[i] = (0.25f*(t00+t01+t10+t11) >= 0.1f) ? 1.0f : 0.0f;
}

// Fused separable 7x7 edge-clamped gaussian; blockIdx.z selects field pair.
__global__ void k_blur2(const float* __restrict__ in0, const float* __restrict__ in1,
                        float* __restrict__ out0, float* __restrict__ out1,
                        const float* __restrict__ m0, const float* __restrict__ m1){
  const int z = blockIdx.z;
  const float* in  = z ? in1 : in0;
  float* out       = z ? out1 : out0;
  const float* msk = z ? m1 : m0;
  const int r0 = blockIdx.x * 16;
  const int bb = blockIdx.y;
  const int tid = threadIdx.x;
  const float* I = in + (bb<<14);
  __shared__ float raw[22][LR];
  __shared__ float hb[22][LR];
  for (int idx = tid; idx < 22*LR; idx += 256){
    int lr = idx >> 7, c = idx & (LR-1);
    int gr = clampi(r0 - 3 + lr, 0, LR-1);
    raw[lr][c] = I[(gr<<7) + c];
  }
  __syncthreads();
  for (int idx = tid; idx < 22*LR; idx += 256){
    int lr = idx >> 7, c = idx & (LR-1);
    float s = 0.f;
    #pragma unroll
    for (int t=-3;t<=3;++t) s += gk(t)*raw[lr][clampi(c+t,0,LR-1)];
    hb[lr][c] = s;
  }
  __syncthreads();
  for (int idx = tid; idx < 16*LR; idx += 256){
    int lr = idx >> 7, c = idx & (LR-1);
    int i = r0 + lr;
    float s = 0.f;
    #pragma unroll
    for (int t=-3;t<=3;++t) s += gk(t)*hb[clampi(i+t,0,LR-1) - (r0-3)][c];
    int gi = (bb<<14) + (i<<7) + c;
    if (msk) s *= msk[gi];
    out[gi] = s;
  }
}

// --- DPP wave64 inclusive prefix (rocPRIM scan sequence), pure VALU ---
template<int CTRL, int RM>
__device__ __forceinline__ float dpp_mov0(float x){
  return __int_as_float(__builtin_amdgcn_update_dpp(0, __float_as_int(x), CTRL, RM, 0xF, true));
}
__device__ __forceinline__ float prefix64(float x){
  x += dpp_mov0<0x111,0xF>(x);   // row_shr:1
  x += dpp_mov0<0x112,0xF>(x);   // row_shr:2
  x += dpp_mov0<0x114,0xF>(x);   // row_shr:4
  x += dpp_mov0<0x118,0xF>(x);   // row_shr:8
  x += dpp_mov0<0x142,0xA>(x);   // row_bcast:15 -> rows 1,3
  x += dpp_mov0<0x143,0xC>(x);   // row_bcast:31 -> rows 2,3
  return x;
}
__device__ __forceinline__ float bperm(int addr4, float v){
  return __int_as_float(__builtin_amdgcn_ds_bpermute(addr4, __float_as_int(v)));
}

struct TapCtx { int ia0, ib0, ia1, ib1; bool la0hi, lb0ok, lb1hi, selA, selB; };

// Horizontal 21-tap zero-pad box via prefix-diff over the 128-col row held as
// (col=lane in v0, col=lane+64 in v1); register argmin update.
__device__ __forceinline__ void horiz_update(const TapCtx& tc, float v0, float v1, int s,
                                             unsigned long long& k0ref, unsigned long long& k1ref){
  float pf0 = prefix64(v0);
  float pf1 = prefix64(v1);
  float T0 = __int_as_float(__builtin_amdgcn_readlane(__float_as_int(pf0), 63));
  float va = tc.selA ? pf0 : pf1;      // va(t) = t>=10 ? pf0 : pf1
  float vb = tc.selB ? pf0 : pf1;      // vb(t) = t>=53 ? pf0 : pf1
  float a0 = bperm(tc.ia0, va) + (tc.la0hi ? T0 : 0.f);   // pf(lane+10)
  float b0 = tc.lb0ok ? bperm(tc.ib0, pf0) : 0.f;         // pf(lane-11) or 0
  float a1 = bperm(tc.ia1, pf1) + T0;                     // pf(min(lane+74,127))
  float b1 = bperm(tc.ib1, vb) + (tc.lb1hi ? T0 : 0.f);   // pf(lane+53)
  float c0 = fmaxf((a0 - b0) * (1.0f/441.0f), 0.f);
  float c1 = fmaxf((a1 - b1) * (1.0f/441.0f), 0.f);
  unsigned long long k0 = ((unsigned long long)__float_as_uint(c0) << 32) | (unsigned)s;
  unsigned long long k1 = ((unsigned long long)__float_as_uint(c1) << 32) | (unsigned)s;
  if (k0 < k0ref) k0ref = k0;
  if (k1 < k1ref) k1ref = k1;
}

// Block = (row-tile of 8, batch), 512 threads = 8 waves, 1 block/CU.
// prev rows in regs (global loads); curr 28-row register window per dx-group,
// slid one row per dy (dx-major shift walk). Vertical box slid over io; horizontal
// via DPP prefix + bpermute taps. Register argmin, slotted LDS merge, flow*rain out.
__global__ void __launch_bounds__(512, 2)
k_cost_flow(const float* __restrict__ prev, const float* __restrict__ curr,
            const float* __restrict__ rain,
            float* __restrict__ fx, float* __restrict__ fy){
  const int r0 = blockIdx.x * TH;
  const int bb = blockIdx.y;
  const int tid = threadIdx.x;
  const int w = tid >> 6, lane = tid & 63;
  const float* P = prev + (bb<<14);
  const float* C = curr + (bb<<14);

  __shared__ float currT[40][LR];                 // rows r0-16..r0+23 (clamped), 20 KB
  __shared__ unsigned long long mg[4][TH*LR];     // merge slots, 32 KB

  for (int idx = tid; idx < 40*LR; idx += 512){
    int lr = idx >> 7, c = idx & (LR-1);
    int gr = clampi(r0 - 16 + lr, 0, LR-1);
    currT[lr][c] = C[(gr<<7) + c];
  }

  // prev rows r0-10..r0+17 at cols (lane, lane+64), zero-pad out of range
  float p0[28], p1[28];
  #pragma unroll
  for (int wr = 0; wr < 28; ++wr){
    int gr = r0 - 10 + wr;
    if (gr >= 0 && gr < LR){ p0[wr] = P[(gr<<7) + lane]; p1[wr] = P[(gr<<7) + lane + 64]; }
    else                   { p0[wr] = 0.f; p1[wr] = 0.f; }
  }
  __syncthreads();

  unsigned long long bk0[TH], bk1[TH];
  #pragma unroll
  for (int io = 0; io < TH; ++io){ bk0[io] = ~0ULL; bk1[io] = ~0ULL; }

  TapCtx tc;
  tc.ia0 = ((lane + 10) & 63) << 2;
  tc.ib0 = ((lane - 11) & 63) << 2;
  tc.ia1 = (min(lane + 10, 63)) << 2;
  tc.ib1 = ((lane + 53) & 63) << 2;
  tc.la0hi = (lane >= 54);
  tc.lb0ok = (lane >= 11);
  tc.lb1hi = (lane >= 11);
  tc.selA  = (lane >= 10);
  tc.selB  = (lane >= 53);

  const int t_lo = (NSHIFT * w) / NW;
  const int t_hi = (NSHIFT * (w+1)) / NW;

  int t = t_lo;
  while (t < t_hi){
    const int dxi  = t / NSH;                    // dx-major walk: t = dxi*13 + dyi
    const int dyi0 = t - dxi*NSH;
    const int ndy  = min(NSH - dyi0, t_hi - t);
    const int dx   = dxi - 6;
    const int c0   = clampi(lane + dx, 0, LR-1);
    const int c1   = clampi(lane + 64 + dx, 0, LR-1);
    // curr register window: rows dyi0..dyi0+27 of currT
    float q0[28], q1[28];
    #pragma unroll
    for (int wr = 0; wr < 28; ++wr){
      q0[wr] = currT[wr + dyi0][c0];
      q1[wr] = currT[wr + dyi0][c1];
    }
    int s = dyi0*NSH + dxi;                      // reference (dy-major) shift index
    for (int rep = 0; rep < ndy; ++rep){
      float v0 = 0.f, v1 = 0.f;
      #pragma unroll
      for (int wr = 0; wr <= 20; ++wr){
        if (r0 - 10 + wr >= 0 && r0 - 10 + wr < LR){   // wave-uniform
          float d0 = p0[wr] - q0[wr];
          float d1 = p1[wr] - q1[wr];
          v0 = fmaf(d0, d0, v0);
          v1 = fmaf(d1, d1, v1);
        }
      }
      horiz_update(tc, v0, v1, s, bk0[0], bk1[0]);
      #pragma unroll
      for (int io = 1; io < TH; ++io){
        {
          const int wrA = io + 20;                     // add leading row
          if (r0 - 10 + wrA < LR){
            float d0 = p0[wrA] - q0[wrA];
            float d1 = p1[wrA] - q1[wrA];
            v0 = fmaf(d0, d0, v0);
            v1 = fmaf(d1, d1, v1);
          }
          const int wrS = io - 1;                      // subtract trailing row
          if (r0 - 10 + wrS >= 0){
            float d0 = p0[wrS] - q0[wrS];
            float d1 = p1[wrS] - q1[wrS];
            v0 = fmaf(-d0, d0, v0);
            v1 = fmaf(-d1, d1, v1);
          }
        }
        horiz_update(tc, v0, v1, s, bk0[io], bk1[io]);
      }
      if (rep < ndy - 1){
        #pragma unroll
        for (int wr = 0; wr < 27; ++wr){ q0[wr] = q0[wr+1]; q1[wr] = q1[wr+1]; }
        q0[27] = currT[dyi0 + rep + 28][c0];
        q1[27] = currT[dyi0 + rep + 28][c1];
      }
      s += NSH;
    }
    t += ndy;
  }

  // slotted tree merge: slot g=w&3, waves 0-3 write, 4-7 merge, then 4-slot min
  __syncthreads();
  const int g = w & 3;
  if (w < 4){
    #pragma unroll
    for (int io = 0; io < TH; ++io){
      mg[g][io*LR + lane]      = bk0[io];
      mg[g][io*LR + lane + 64] = bk1[io];
    }
  }
  __syncthreads();
  if (w >= 4){
    #pragma unroll
    for (int io = 0; io < TH; ++io){
      unsigned long long m0 = mg[g][io*LR + lane];
      unsigned long long m1 = mg[g][io*LR + lane + 64];
      mg[g][io*LR + lane]      = (bk0[io] < m0) ? bk0[io] : m0;
      mg[g][io*LR + lane + 64] = (bk1[io] < m1) ? bk1[io] : m1;
    }
  }
  __syncthreads();
  for (int p = tid; p < TH*LR; p += 512){
    unsigned long long k  = mg[0][p];
    unsigned long long k1 = mg[1][p]; if (k1 < k) k = k1;
    unsigned long long k2 = mg[2][p]; if (k2 < k) k = k2;
    unsigned long long k3 = mg[3][p]; if (k3 < k) k = k3;
    int s = (int)(k & 0xffffffffULL);
    int io = p >> 7, jj = p & (LR-1);
    int gi = (bb<<14) + ((r0+io)<<7) + jj;
    float r = rain[gi];
    fx[gi] = (float)(s % NSH - 6) * r;
    fy[gi] = (float)(s / NSH - 6) * r;
  }
}

// Fused: flow upsample (x4), warp of ref (border bilinear), Huber+mask, mean-reduce.
// Thread = 2 groups of 4 px; 12 shared flow loads/group (wx,wy are exact constants
// per x&3/y&3); per-px bilinear keeps round-3 operand order exactly.
__global__ void __launch_bounds__(256)
k_loss(const float* __restrict__ pred, const float* __restrict__ tar,
       const float* __restrict__ ref, const float* __restrict__ fxb,
       const float* __restrict__ fyb, float* __restrict__ out){
  const int t0 = blockIdx.x*256 + threadIdx.x;   // 0..524287
  float acc = 0.f;
  #pragma unroll
  for (int it = 0; it < 2; ++it){
    const int gq  = t0 + it*524288;
    const int b   = gq >> 16;
    const int rem = gq & 65535;
    const int y   = rem >> 7;
    const int m   = rem & 127;
    const int n = y >> 2, ky = y & 3;
    int y0; float wy;
    if (ky < 2){ y0 = max(n-1, 0); wy = (n >= 1) ? (ky == 0 ? 0.625f : 0.875f) : 0.f; }
    else       { y0 = n;           wy = (ky == 2) ? 0.125f : 0.375f; }
    const int y1 = min(y0+1, LR-1);
    const int lb = b << 14;
    const float* FxR0 = fxb + lb + (y0<<7);
    const float* FxR1 = fxb + lb + (y1<<7);
    const float* FyR0 = fyb + lb + (y0<<7);
    const float* FyR1 = fyb + lb + (y1<<7);
    const int cA = max(m-1, 0), cB = m, cC = min(m+1, LR-1);
    float xA0 = FxR0[cA], xB0 = FxR0[cB], xC0 = FxR0[cC];
    float xA1 = FxR1[cA], xB1 = FxR1[cB], xC1 = FxR1[cC];
    float yA0 = FyR0[cA], yB0 = FyR0[cB], yC0 = FyR0[cC];
    float yA1 = FyR1[cA], yB1 = FyR1[cB], yC1 = FyR1[cC];
    const bool mh = (m >= 1);
    const int hb = (b<<18) + (y<<9) + (m<<2);
    float4 pd = *(const float4*)(pred + hb);
    float4 td = *(const float4*)(tar + hb);
    const float* R = ref + (b<<18);
    const float wy1 = 1.f - wy;
    #pragma unroll
    for (int k = 0; k < 4; ++k){
      float wx;
      float lo0, hi0, lo1, hi1, flo0, fhi0, flo1, fhi1;
      if (k < 2){
        wx = mh ? (k == 0 ? 0.625f : 0.875f) : 0.f;
        lo0 = mh ? xA0 : xB0;  hi0 = mh ? xB0 : xC0;
        lo1 = mh ? xA1 : xB1;  hi1 = mh ? xB1 : xC1;
        flo0 = mh ? yA0 : yB0; fhi0 = mh ? yB0 : yC0;
        flo1 = mh ? yA1 : yB1; fhi1 = mh ? yB1 : yC1;
      } else {
        wx = (k == 2) ? 0.125f : 0.375f;
        lo0 = xB0;  hi0 = xC0;  lo1 = xB1;  hi1 = xC1;
        flo0 = yB0; fhi0 = yC0; flo1 = yB1; fhi1 = yC1;
      }
      const float w00 = wy1*(1.f-wx), w01 = wy1*wx, w10 = wy*(1.f-wx), w11 = wy*wx;
      const float fxv = 4.f*(w00*lo0 + w01*hi0 + w10*lo1 + w11*hi1);
      const float fyv = 4.f*(w00*flo0 + w01*fhi0 + w10*flo1 + w11*fhi1);
      const int x = (m<<2) + k;
      float ix = fminf(fmaxf((float)x - fxv, 0.f), (float)(HR-1));
      float iy = fminf(fmaxf((float)y - fyv, 0.f), (float)(HR-1));
      int gx0 = (int)ix; int gx1 = min(gx0+1, HR-1); float gwx = ix - (float)gx0;
      int gy0 = (int)iy; int gy1 = min(gy0+1, HR-1); float gwy = iy - (float)gy0;
      float v00 = R[(gy0<<9)+gx0], v01 = R[(gy0<<9)+gx1];
      float v10 = R[(gy1<<9)+gx0], v11 = R[(gy1<<9)+gx1];
      float tt = v00*(1.f-gwy)*(1.f-gwx) + v01*(1.f-gwy)*gwx
               + v10*gwy*(1.f-gwx)       + v11*gwy*gwx;
      float teacher = fmaxf(tt, 0.f);
      float pk = ((const float*)&pd)[k];
      float tk = ((const float*)&td)[k];
      float d  = pk - teacher;
      float ad = fabsf(d);
      float l  = ad < 0.2f ? 0.5f*d*d : 0.2f*(ad - 0.1f);
      float mm = (teacher > 0.05f || tk > 0.05f) ? 1.f : 0.f;
      acc += l*mm;
    }
  }
  acc *= (1.0f/(float)N_HR);
  #pragma unroll
  for (int o = 32; o > 0; o >>= 1) acc += __shfl_down(acc, o, 64);
  __shared__ float wsum[4];
  int lane = threadIdx.x & 63, wv = threadIdx.x >> 6;
  if (lane == 0) wsum[wv] = acc;
  __syncthreads();
  if (threadIdx.x == 0) atomicAdd(out, wsum[0]+wsum[1]+wsum[2]+wsum[3]);
}

extern "C" void kernel_launch(void* const* d_in, const int* in_sizes, int n_in,
                              void* d_out, int out_size, void* d_ws, size_t ws_size,
                              hipStream_t stream){
  const float* pred = (const float*)d_in[0];
  const float* tar  = (const float*)d_in[1];
  const float* ref  = (const float*)d_in[2];
  float* out = (float*)d_out;
  float* w = (float*)d_ws;
  float* prevW = w + 0*N_LR;
  float* currW = w + 1*N_LR;
  float* rain  = w + 2*N_LR;
  float* fxb   = w + 3*N_LR;
  float* fyb   = w + 4*N_LR;
  float* dsA   = w + 5*N_LR;   // wref_ds, later reused as raw fx
  float* dsB   = w + 6*N_LR;   // wtar_ds, later reused as raw fy

  hipMemsetAsync(d_out, 0, sizeof(float), stream);

  const int tb = 256, nb = (N_LR + tb - 1)/tb;
  k_downsample<<<nb, tb, 0, stream>>>(ref, tar, dsA, dsB, rain);
  k_blur2<<<dim3(8, BATCH, 2), tb, 0, stream>>>(dsA, dsB, prevW, currW, nullptr, nullptr);
  k_cost_flow<<<dim3(LR/TH, BATCH), 512, 0, stream>>>(prevW, currW, rain, dsA, dsB);
  k_blur2<<<dim3(8, BATCH, 2), tb, 0, stream>>>(dsA, dsB, fxb, fyb, rain, rain);
  k_loss<<<2048, tb, 0, stream>>>(pred, tar, ref, fxb, fyb, out);
}